// Round 4
// baseline (201.533 us; speedup 1.0000x reference)
//
#include <hip/hip_runtime.h>
#include <cstdint>
#include <cstddef>

// Problem constants (from reference setup_inputs)
#define BB 16
#define CC 7
#define HH 368
#define WW 640
#define LL (HH * WW)          // 235520 pixels per batch
#define NCLS 6                // classes 1..6 (background 0 skipped)
#define NCOMBO (BB * NCLS)    // 96
#define PXT 16                // pixels per thread
#define TPB 64                // threads per block (1 wave) -> 1024 px/block
#define PXB (PXT * TPB)       // 1024
#define BPB (LL / PXB)        // 230 blocks per batch
#define NBLK (BB * BPB)       // 3680 blocks total (= 3680 waves, was 14720)

// Order-preserving monoid over a contiguous pixel range (per class):
//   S   = sum of |d_i - d_prev| over consecutive masked pixels inside range
//   cnt = masked pixel count; first/last = d of first/last masked pixel
// Identity: cnt == 0. Combine adds the bridging |B.first - A.last|.
struct St { int S, cnt, first, last; };

__device__ inline St comb(const St& a, const St& b) {
    // Branchless: identity handled by cnt==0 selects.
    St r;
    int both = (a.cnt > 0) & (b.cnt > 0);
    r.S     = a.S + b.S + (both ? abs(b.first - a.last) : 0);
    r.cnt   = a.cnt + b.cnt;
    r.first = (a.cnt > 0) ? a.first : b.first;
    r.last  = (b.cnt > 0) ? b.last : a.last;
    return r;
}

__device__ inline St shfl_down_st(const St& s, int off) {
    St r;
    r.S     = __shfl_down(s.S, off, 64);
    r.cnt   = __shfl_down(s.cnt, off, 64);
    r.first = __shfl_down(s.first, off, 64);
    r.last  = __shfl_down(s.last, off, 64);
    return r;
}

// ---------------------------------------------------------------------------
// Kernel 1 (fused): soft-argmax -> floor -> per-class monoid scan.
// One wave per block, 16 contiguous px per thread (16 | 640 and the start is
// 16-aligned -> a thread's pixels never cross a row). No LDS, no barriers:
// the 256->1 LDS tree of R3 (42 us of LDS pipe + 3.1M conflict cycles) is
// replaced by a 64->1 shfl_down tree (~430 VALU inst per wave).
// The shfl_down power-of-2 tree is order-safe for the non-commutative monoid:
// lane 0 only consumes lanes holding complete contiguous ranges.
// Output: blkStates[cls][blk] (class-major so kernel 2 reads coalesce).
// ---------------------------------------------------------------------------
__global__ __launch_bounds__(64) void fused_kernel(const float* __restrict__ logits,
                                                   int4* __restrict__ blkStates) {
    int blk = blockIdx.x;
    int b  = blk / BPB;
    int bb = blk - b * BPB;
    int t  = threadIdx.x;
    int i  = bb * PXB + t * PXT;          // pixel index within batch, 16-aligned
    const float* base = logits + (size_t)b * CC * LL + i;

    int row = i / WW;
    int col = i - row * WW;
    int d0  = col - row;                  // d for px k of this thread = d0 + k

    St st[NCLS];
#pragma unroll
    for (int c = 0; c < NCLS; ++c) { st[c].S = 0; st[c].cnt = 0; st[c].first = 0; st[c].last = 0; }

#pragma unroll
    for (int j = 0; j < PXT / 4; ++j) {   // 4 batches of 4 pixels
        float x[CC][4];
#pragma unroll
        for (int c = 0; c < CC; ++c) {
            float4 v = *reinterpret_cast<const float4*>(base + (size_t)c * LL + j * 4);
            x[c][0] = v.x; x[c][1] = v.y; x[c][2] = v.z; x[c][3] = v.w;
        }
#pragma unroll
        for (int k = 0; k < 4; ++k) {
            float m = x[0][k];
#pragma unroll
            for (int c = 1; c < CC; ++c) m = fmaxf(m, x[c][k]);
            float s = 0.0f, w = 0.0f;
#pragma unroll
            for (int c = 0; c < CC; ++c) {
                float e = __expf(x[c][k] - m);
                s += e;
                w += e * (float)c;
            }
            // soft_argmax = (sum e_c * c) / (sum e_c); only its floor matters.
            int sv = (int)floorf(__fdividef(w, s));
            int d  = d0 + j * 4 + k;
#pragma unroll
            for (int c = 0; c < NCLS; ++c) {
                if (sv == c + 1) {
                    if (st[c].cnt == 0) st[c].first = d;
                    else                st[c].S += abs(d - st[c].last);
                    st[c].last = d;
                    st[c].cnt++;
                }
            }
        }
    }

    // Ordered wave reduce: after step `off`, lane t holds the combine of
    // lanes [t, t+2*off) where complete; lane 0 ends with the full range.
#pragma unroll
    for (int c = 0; c < NCLS; ++c) {
        St s = st[c];
#pragma unroll
        for (int off = 1; off < 64; off <<= 1) {
            St o = shfl_down_st(s, off);
            s = comb(s, o);
        }
        st[c] = s;
    }

    if (t == 0) {
#pragma unroll
        for (int c = 0; c < NCLS; ++c)
            blkStates[(size_t)c * NBLK + blk] = make_int4(st[c].S, st[c].cnt, st[c].first, st[c].last);
    }
}

// ---------------------------------------------------------------------------
// Kernel 2: per (batch, class) combine the 230 per-block states in order,
// then atomicAdd the combo's contribution into out[0]. 256 threads (4 waves):
// shfl-reduce per wave, tiny LDS combine of the 4 wave results in order.
// out[0] is zeroed by a hipMemsetAsync graph node each call.
// ---------------------------------------------------------------------------
__global__ __launch_bounds__(256) void combine_kernel(const int4* __restrict__ blkStates,
                                                      float* __restrict__ out) {
    int combo = blockIdx.x;               // b * NCLS + (cls-1)
    int b = combo / NCLS;
    int c = combo - b * NCLS;
    int t = threadIdx.x;

    St st{0, 0, 0, 0};
    if (t < BPB) {
        int4 v = blkStates[(size_t)c * NBLK + b * BPB + t];   // coalesced
        st = St{v.x, v.y, v.z, v.w};
    }

#pragma unroll
    for (int off = 1; off < 64; off <<= 1) {
        St o = shfl_down_st(st, off);
        st = comb(st, o);
    }

    __shared__ int4 ws[4];
    int wave = t >> 6;
    if ((t & 63) == 0) ws[wave] = make_int4(st.S, st.cnt, st.first, st.last);
    __syncthreads();

    if (t == 0) {
        St acc{ws[0].x, ws[0].y, ws[0].z, ws[0].w};
#pragma unroll
        for (int w = 1; w < 4; ++w) {
            St o{ws[w].x, ws[w].y, ws[w].z, ws[w].w};
            acc = comb(acc, o);
        }
        int n = acc.cnt;
        if (n >= 2) {
            // npairs = n-1; mean = S / npairs; contribution = mean / (n+1)
            double res = ((double)acc.S / (double)(n - 1)) / (double)(n + 1);
            atomicAdd(out, (float)res);
        }
    }
}

extern "C" void kernel_launch(void* const* d_in, const int* in_sizes, int n_in,
                              void* d_out, int out_size, void* d_ws, size_t ws_size,
                              hipStream_t stream) {
    const float* logits = (const float*)d_in[0];
    // d_in[1] (labels) is unused by the reference computation.
    float* out = (float*)d_out;

    int4* blkStates = (int4*)d_ws;        // 6 * 3680 * 16 = 353280 B

    // d_out is re-poisoned to 0xAA before every replay -> zero it (async,
    // graph-capturable memset node).
    hipMemsetAsync(out, 0, sizeof(float) * out_size, stream);
    fused_kernel<<<NBLK, TPB, 0, stream>>>(logits, blkStates);
    combine_kernel<<<NCOMBO, 256, 0, stream>>>(blkStates, out);
}

// Round 5
// 166.748 us; speedup vs baseline: 1.2086x; 1.2086x over previous
//
#include <hip/hip_runtime.h>
#include <cstdint>
#include <cstddef>

// Problem constants (from reference setup_inputs)
#define BB 16
#define CC 7
#define HH 368
#define WW 640
#define LL (HH * WW)          // 235520 pixels per batch
#define NCLS 6                // classes 1..6 (background 0 skipped)
#define NCOMBO (BB * NCLS)    // 96
#define PXW 256               // pixels per wave (64 lanes x 4 px)
#define PXB 1024              // pixels per block (4 waves)
#define BPB (LL / PXB)        // 230 blocks per batch
#define NBLK (BB * BPB)       // 3680 blocks total

// Order-preserving monoid over a contiguous pixel range (per class):
//   S   = sum of |d_i - d_prev| over consecutive masked pixels inside range
//   cnt = masked pixel count; first/last = d of first/last masked pixel
// Identity: cnt == 0. Combine adds the bridging |B.first - A.last|.
struct St { int S, cnt, first, last; };

__device__ inline St comb(const St& a, const St& b) {
    St r;
    int both = (a.cnt > 0) & (b.cnt > 0);
    r.S     = a.S + b.S + (both ? abs(b.first - a.last) : 0);
    r.cnt   = a.cnt + b.cnt;
    r.first = (a.cnt > 0) ? a.first : b.first;
    r.last  = (b.cnt > 0) ? b.last : a.last;
    return r;
}

__device__ inline St shfl_down_st(const St& s, int off) {
    St r;
    r.S     = __shfl_down(s.S, off, 64);
    r.cnt   = __shfl_down(s.cnt, off, 64);
    r.first = __shfl_down(s.first, off, 64);
    r.last  = __shfl_down(s.last, off, 64);
    return r;
}

// ---------------------------------------------------------------------------
// Kernel 1 (fused): soft-argmax -> floor -> per-class monoid scan.
// R3's coalesced load pattern (4 px/thread, lanes 16 B apart -> one 1-KiB
// transaction per wave load, FETCH was 51.6 MB) + R4's shfl reduce (no LDS
// tree -> R3's 3.1M conflict cycles / 42 us of LDS pipe gone).
// 256 threads = 4 waves; wave w owns the contiguous 256-px segment
// [w*256, (w+1)*256) of the block's 1024 px, so the per-wave shfl_down tree
// and the 4-wave LDS combine (384 B) both respect pixel order.
// Per-class __ballot skip: seg concentrates in classes 2-3, so most waves
// skip most class trees.
// Output: blkStates[cls][blk] (class-major so kernel 2 reads coalesce).
// ---------------------------------------------------------------------------
__global__ __launch_bounds__(256) void fused_kernel(const float* __restrict__ logits,
                                                    int4* __restrict__ blkStates) {
    int blk = blockIdx.x;
    int b   = blk / BPB;
    int bb  = blk - b * BPB;
    int t   = threadIdx.x;
    int w   = t >> 6;                     // wave 0..3
    int lane = t & 63;
    int i   = bb * PXB + w * PXW + lane * 4;  // pixel index within batch, 16B aligned
    const float* base = logits + (size_t)b * CC * LL + i;

    float x[CC][4];
#pragma unroll
    for (int c = 0; c < CC; ++c) {
        float4 v = *reinterpret_cast<const float4*>(base + (size_t)c * LL);
        x[c][0] = v.x; x[c][1] = v.y; x[c][2] = v.z; x[c][3] = v.w;
    }

    // 4 | 640 and i % 4 == 0 -> the 4-pixel group never crosses a row.
    int row = i / WW;
    int col = i - row * WW;
    int d0  = col - row;

    St st[NCLS];
#pragma unroll
    for (int c = 0; c < NCLS; ++c) { st[c].S = 0; st[c].cnt = 0; st[c].first = 0; st[c].last = 0; }

#pragma unroll
    for (int k = 0; k < 4; ++k) {
        float m = x[0][k];
#pragma unroll
        for (int c = 1; c < CC; ++c) m = fmaxf(m, x[c][k]);
        float s = 0.0f, wsum = 0.0f;
#pragma unroll
        for (int c = 0; c < CC; ++c) {
            float e = __expf(x[c][k] - m);
            s += e;
            wsum += e * (float)c;
        }
        // soft_argmax = (sum e_c * c) / (sum e_c); only its floor matters.
        int sv = (int)floorf(__fdividef(wsum, s));
        int d  = d0 + k;
#pragma unroll
        for (int c = 0; c < NCLS; ++c) {
            if (sv == c + 1) {
                if (st[c].cnt == 0) st[c].first = d;
                else                st[c].S += abs(d - st[c].last);
                st[c].last = d;
                st[c].cnt++;
            }
        }
    }

    __shared__ int4 sw[NCLS][4];          // 384 B: per-class per-wave states

    // Ordered wave reduce per class; skip classes absent from this wave.
#pragma unroll
    for (int c = 0; c < NCLS; ++c) {
        St s = st[c];
        if (__ballot(s.cnt > 0) == 0ull) {
            if (lane == 0) sw[c][w] = make_int4(0, 0, 0, 0);
            continue;
        }
#pragma unroll
        for (int off = 1; off < 64; off <<= 1) {
            St o = shfl_down_st(s, off);
            s = comb(s, o);
        }
        if (lane == 0) sw[c][w] = make_int4(s.S, s.cnt, s.first, s.last);
    }
    __syncthreads();

    // Threads 0..5: combine the 4 wave states (in wave order) for class t.
    if (t < NCLS) {
        St acc{sw[t][0].x, sw[t][0].y, sw[t][0].z, sw[t][0].w};
#pragma unroll
        for (int q = 1; q < 4; ++q) {
            St o{sw[t][q].x, sw[t][q].y, sw[t][q].z, sw[t][q].w};
            acc = comb(acc, o);
        }
        blkStates[(size_t)t * NBLK + blk] = make_int4(acc.S, acc.cnt, acc.first, acc.last);
    }
}

// ---------------------------------------------------------------------------
// Kernel 2: per (batch, class) combine the 230 per-block states in order,
// then atomicAdd the combo's contribution into out[0]. 256 threads (4 waves):
// shfl-reduce per wave, tiny LDS combine of the 4 wave results in order.
// out[0] is zeroed by a hipMemsetAsync graph node each call.
// ---------------------------------------------------------------------------
__global__ __launch_bounds__(256) void combine_kernel(const int4* __restrict__ blkStates,
                                                      float* __restrict__ out) {
    int combo = blockIdx.x;               // b * NCLS + (cls-1)
    int b = combo / NCLS;
    int c = combo - b * NCLS;
    int t = threadIdx.x;

    St st{0, 0, 0, 0};
    if (t < BPB) {
        int4 v = blkStates[(size_t)c * NBLK + b * BPB + t];   // coalesced
        st = St{v.x, v.y, v.z, v.w};
    }

#pragma unroll
    for (int off = 1; off < 64; off <<= 1) {
        St o = shfl_down_st(st, off);
        st = comb(st, o);
    }

    __shared__ int4 ws[4];
    int wave = t >> 6;
    if ((t & 63) == 0) ws[wave] = make_int4(st.S, st.cnt, st.first, st.last);
    __syncthreads();

    if (t == 0) {
        St acc{ws[0].x, ws[0].y, ws[0].z, ws[0].w};
#pragma unroll
        for (int w = 1; w < 4; ++w) {
            St o{ws[w].x, ws[w].y, ws[w].z, ws[w].w};
            acc = comb(acc, o);
        }
        int n = acc.cnt;
        if (n >= 2) {
            // npairs = n-1; mean = S / npairs; contribution = mean / (n+1)
            double res = ((double)acc.S / (double)(n - 1)) / (double)(n + 1);
            atomicAdd(out, (float)res);
        }
    }
}

extern "C" void kernel_launch(void* const* d_in, const int* in_sizes, int n_in,
                              void* d_out, int out_size, void* d_ws, size_t ws_size,
                              hipStream_t stream) {
    const float* logits = (const float*)d_in[0];
    // d_in[1] (labels) is unused by the reference computation.
    float* out = (float*)d_out;

    int4* blkStates = (int4*)d_ws;        // 6 * 3680 * 16 = 353280 B

    // d_out is re-poisoned to 0xAA before every replay -> zero it (async,
    // graph-capturable memset node).
    hipMemsetAsync(out, 0, sizeof(float) * out_size, stream);
    fused_kernel<<<NBLK, 256, 0, stream>>>(logits, blkStates);
    combine_kernel<<<NCOMBO, 256, 0, stream>>>(blkStates, out);
}